// Round 4
// baseline (303.476 us; speedup 1.0000x reference)
//
#include <hip/hip_runtime.h>

typedef float f4 __attribute__((ext_vector_type(4)));

#define BK 16
#define TN 64          // n-rows and m-rows per block
#define TO 64          // o-cols per block
#define NTILES 48      // 768 / BK

// One fused kernel. Block = (b, n-tile 64, m-tile 64, o-slice 64).
// Phase 1: GEMM p1[64n][64o] = input1-tile @ W1-slice, p2[64m][64o] = input2-tile @ W2-slice
//          (double-buffered LDS, issue->compute->stage->barrier pipeline, fp32 FMA).
// Phase 2: out[b,n,m,o] = p1[n,o] + p2[m,o] + bias[o], non-temporal f4 stores.
// Thread (tr,tc) owns p1 rows tr*4..+3 at cols tc*4..+3 == exactly the p1 fragments the
// broadcast phase needs -> p1 stays in registers; only p2 redistributes through LDS.
// Recompute: total FMA = 2.42 GFLOP (2x minimal) ~= 20 us VALU; store floor 201 MB ~= 31 us.
__global__ __launch_bounds__(256) void fused_kernel(
    const float* __restrict__ A1, const float* __restrict__ A2,
    const float* __restrict__ W, const float* __restrict__ bias,
    float* __restrict__ out)
{
    __shared__ union {
        float stage[2][4][BK][TN + 4];   // [dbuf][a1,a2,w1,w2][k][row] = 34.8 KB
        float pp2[TN][TO + 4];           // p2 tile for broadcast      = 17.4 KB
    } u;

    const int o0 = blockIdx.x * TO;      // 0..11 -> o slice
    const int nm = blockIdx.y;           // 0..15
    const int b  = nm >> 2;
    const int n0 = ((nm >> 1) & 1) * TN;
    const int m0 = (nm & 1) * TN;
    const int t  = threadIdx.x;

    // global-load mapping
    const int ln  = t >> 2;              // 0..63: A row
    const int lk4 = (t & 3) * 4;         // 0,4,8,12: A k-offset (f4 along k, coalesced)
    const int wk  = t >> 4;              // 0..15: W k-row
    const int wo4 = (t & 15) * 4;        // 0..60: W o-offset (f4 along o, coalesced)

    const float* a1p = A1 + (size_t)(b * 128 + n0 + ln) * 768 + lk4;
    const float* a2p = A2 + (size_t)(b * 128 + m0 + ln) * 768 + lk4;
    const float* w1p = W + (size_t)wk * 768 + o0 + wo4;
    const float* w2p = W + (size_t)(768 + wk) * 768 + o0 + wo4;

    // compute mapping: 16x16 thread grid, 4x4 micro-tile for each of p1,p2
    const int tr = t >> 4;               // rows tr*4..+3
    const int tc = t & 15;               // cols tc*4..+3

    // prologue: load + stage tile 0
    f4 a1v = *(const f4*)(a1p);
    f4 a2v = *(const f4*)(a2p);
    f4 w1v = *(const f4*)(w1p);
    f4 w2v = *(const f4*)(w2p);
    #pragma unroll
    for (int i = 0; i < 4; ++i) {
        u.stage[0][0][lk4 + i][ln] = a1v[i];   // transposed: 2-way bank alias = free
        u.stage[0][1][lk4 + i][ln] = a2v[i];
    }
    *(f4*)&u.stage[0][2][wk][wo4] = w1v;
    *(f4*)&u.stage[0][3][wk][wo4] = w2v;
    __syncthreads();

    f4 acc1[4] = {};
    f4 acc2[4] = {};
    int cur = 0;

    for (int tt = 0; tt < NTILES; ++tt) {
        // 1) issue next tile's loads (land during compute)
        if (tt + 1 < NTILES) {
            const int k0 = (tt + 1) * BK;
            a1v = *(const f4*)(a1p + k0);
            a2v = *(const f4*)(a2p + k0);
            w1v = *(const f4*)(w1p + (size_t)k0 * 768);
            w2v = *(const f4*)(w2p + (size_t)k0 * 768);
        }
        // 2) compute current buffer: per k, 4 ds_read_b128 + 32 v_fma
        #pragma unroll
        for (int k = 0; k < BK; ++k) {
            const f4 x1 = *(const f4*)&u.stage[cur][0][k][tr * 4];  // broadcast groups
            const f4 x2 = *(const f4*)&u.stage[cur][1][k][tr * 4];
            const f4 y1 = *(const f4*)&u.stage[cur][2][k][tc * 4];  // consecutive f4s
            const f4 y2 = *(const f4*)&u.stage[cur][3][k][tc * 4];
            #pragma unroll
            for (int i = 0; i < 4; ++i) {
                acc1[i] += x1[i] * y1;
                acc2[i] += x2[i] * y2;
            }
        }
        // 3) stage regs -> other buffer (vmcnt wait lands here, after compute)
        if (tt + 1 < NTILES) {
            const int nxt = cur ^ 1;
            #pragma unroll
            for (int i = 0; i < 4; ++i) {
                u.stage[nxt][0][lk4 + i][ln] = a1v[i];
                u.stage[nxt][1][lk4 + i][ln] = a2v[i];
            }
            *(f4*)&u.stage[nxt][2][wk][wo4] = w1v;
            *(f4*)&u.stage[nxt][3][wk][wo4] = w2v;
            __syncthreads();
        }
        cur ^= 1;
    }
    __syncthreads();                     // all stage reads done before union reuse

    // redistribute p2 through LDS (p1 stays in this thread's registers)
    #pragma unroll
    for (int i = 0; i < 4; ++i)
        *(f4*)&u.pp2[tr * 4 + i][tc * 4] = acc2[i];
    __syncthreads();

    // broadcast phase: out[b, n0+tr*4+i, m0+m, o0+tc*4 ..] = p1 + p2 + bias
    const f4 bb = *(const f4*)(bias + o0 + tc * 4);
    f4 p1b[4];
    #pragma unroll
    for (int i = 0; i < 4; ++i)
        p1b[i] = acc1[i] + bb;

    float* ob = out + ((size_t)(b * 128 + n0 + tr * 4) * 128 + m0) * 768 + o0 + tc * 4;

    #pragma unroll 4
    for (int m = 0; m < TN; ++m) {
        const f4 p2v = *(const f4*)&u.pp2[m][tc * 4];   // broadcast + consecutive: conflict-free
        #pragma unroll
        for (int i = 0; i < 4; ++i)
            __builtin_nontemporal_store(p1b[i] + p2v,
                (f4*)(ob + (size_t)i * 128 * 768 + (size_t)m * 768));
    }
}

extern "C" void kernel_launch(void* const* d_in, const int* in_sizes, int n_in,
                              void* d_out, int out_size, void* d_ws, size_t ws_size,
                              hipStream_t stream)
{
    const float* input1 = (const float*)d_in[0];  // (4,128,768)
    const float* input2 = (const float*)d_in[1];  // (4,128,768)
    const float* W      = (const float*)d_in[2];  // (1536,768)
    const float* bias   = (const float*)d_in[3];  // (768,)
    float* out = (float*)d_out;                   // (4,128,128,768)

    // 12 o-slices x 16 (b, n-tile, m-tile) bricks = 192 blocks, 256 threads
    fused_kernel<<<dim3(768 / TO, 16), 256, 0, stream>>>(input1, input2, W, bias, out);
}

// Round 5
// 296.004 us; speedup vs baseline: 1.0252x; 1.0252x over previous
//
#include <hip/hip_runtime.h>

typedef float f4 __attribute__((ext_vector_type(4)));

#define BK 16
#define TT 64          // n-rows (p1) and m-rows (p2) per block
#define TO 64          // o-cols per block
#define NTILES 48      // 768 / BK

// Fused kernel, round 5: 512 threads / 8 waves, wave-specialized.
//   threads   0..255 (waves 0-3): stage + compute p1 = A1-tile @ W1-slice
//   threads 256..511 (waves 4-7): stage + compute p2 = A2-tile @ W2-slice
// Rationale (R4 counters): Occupancy 8% (1 wave/SIMD), VALUBusy 17.8% == the 20 us
// VALU floor / 136 us actual -> latency-bound, not throughput-bound. 8 waves gives
// 2/SIMD so ds_read latency and lgkmcnt waits overlap across waves (m114 mechanism).
// Micro-tile stays 4x4 so the LDS-read:FMA ratio stays 2 B/FMA (LDS ~= VALU ~= 20 us/CU).
// Egress: both p-tiles through LDS (exact union with stage bufs), contiguous NT stores.
__global__ __launch_bounds__(512) void fused_kernel(
    const float* __restrict__ A1, const float* __restrict__ A2,
    const float* __restrict__ W, const float* __restrict__ bias,
    float* __restrict__ out)
{
    __shared__ union {
        float stage[2][4][BK][TT + 4];   // [dbuf][A1,A2,W1,W2][k][row] = 34816 B
        float pp[2][TT][TO + 4];         // [p1,p2][row][col]          = 34816 B
    } u;

    const int o0 = blockIdx.x * TO;      // 12 o-slices
    const int nm = blockIdx.y;           // 16 (b, n-tile, m-tile) bricks
    const int b  = nm >> 2;
    const int n0 = ((nm >> 1) & 1) * TT;
    const int m0 = (nm & 1) * TT;
    const int t  = threadIdx.x;          // 0..511
    const int h  = t >> 8;               // 0 = p1 half, 1 = p2 half
    const int tl = t & 255;              // id within half

    // staging mapping (per half: A-tile 256 f4, W-tile 256 f4; one f4 each, coalesced)
    const int ln  = tl >> 2;             // 0..63: A row
    const int lk4 = (tl & 3) * 4;        // 0,4,8,12: A k-offset
    const int wk  = tl >> 4;             // 0..15: W k-row
    const int wo4 = (tl & 15) * 4;       // 0..60: W o-offset

    const float* Abase = h ? A2 : A1;
    const float* ap = Abase + (size_t)(b * 128 + (h ? m0 : n0) + ln) * 768 + lk4;
    const float* wp = W + (size_t)(h * 768 + wk) * 768 + o0 + wo4;

    // compute mapping: within half, 16x16 threads, 4x4 micro-tile
    const int tr = tl >> 4;              // rows tr*4..+3
    const int tc = tl & 15;              // cols tc*4..+3

    // prologue: load + stage tile 0
    f4 av = *(const f4*)(ap);
    f4 wv = *(const f4*)(wp);
    #pragma unroll
    for (int i = 0; i < 4; ++i)
        u.stage[0][h][lk4 + i][ln] = av[i];    // transposed A: 2-way bank alias = free
    *(f4*)&u.stage[0][2 + h][wk][wo4] = wv;
    __syncthreads();

    f4 acc[4] = {};
    int cur = 0;

    for (int tt = 0; tt < NTILES; ++tt) {
        // 1) issue next tile's loads (land during compute)
        if (tt + 1 < NTILES) {
            const int k0 = (tt + 1) * BK;
            av = *(const f4*)(ap + k0);
            wv = *(const f4*)(wp + (size_t)k0 * 768);
        }
        // 2) compute current buffer: per k, 2 ds_read_b128 + 16 v_fma per thread
        #pragma unroll
        for (int k = 0; k < BK; ++k) {
            const f4 x = *(const f4*)&u.stage[cur][h][k][tr * 4];      // 4-addr broadcast
            const f4 y = *(const f4*)&u.stage[cur][2 + h][k][tc * 4];  // 16 contiguous f4
            #pragma unroll
            for (int i = 0; i < 4; ++i)
                acc[i] += x[i] * y;
        }
        // 3) stage regs -> other buffer (vmcnt wait lands here, after compute)
        if (tt + 1 < NTILES) {
            const int nxt = cur ^ 1;
            #pragma unroll
            for (int i = 0; i < 4; ++i)
                u.stage[nxt][h][lk4 + i][ln] = av[i];
            *(f4*)&u.stage[nxt][2 + h][wk][wo4] = wv;
            __syncthreads();
        }
        cur ^= 1;
    }
    __syncthreads();                     // all stage reads done before union reuse

    // park both p-tiles in LDS
    #pragma unroll
    for (int i = 0; i < 4; ++i)
        *(f4*)&u.pp[h][tr * 4 + i][tc * 4] = acc[i];
    __syncthreads();

    // egress: thread -> (2 n-rows, all 64 m, one f4 of o). 512 threads cover the brick.
    const int o4 = (t & 15) * 4;         // 0..60
    const int nn = t >> 4;               // 0..31 -> n rows nn*2, nn*2+1
    const f4 bb  = *(const f4*)(bias + o0 + o4);
    const f4 p1a = *(const f4*)&u.pp[0][nn * 2 + 0][o4] + bb;
    const f4 p1b = *(const f4*)&u.pp[0][nn * 2 + 1][o4] + bb;

    float* ob = out + ((size_t)(b * 128 + n0 + nn * 2) * 128 + m0) * 768 + o0 + o4;
    const size_t nstride = (size_t)128 * 768;

    #pragma unroll 4
    for (int m = 0; m < TT; ++m) {
        const f4 p2v = *(const f4*)&u.pp[1][m][o4];   // quarter-wave contiguous: min-cycle
        __builtin_nontemporal_store(p1a + p2v, (f4*)(ob + (size_t)m * 768));
        __builtin_nontemporal_store(p1b + p2v, (f4*)(ob + nstride + (size_t)m * 768));
    }
}

extern "C" void kernel_launch(void* const* d_in, const int* in_sizes, int n_in,
                              void* d_out, int out_size, void* d_ws, size_t ws_size,
                              hipStream_t stream)
{
    const float* input1 = (const float*)d_in[0];  // (4,128,768)
    const float* input2 = (const float*)d_in[1];  // (4,128,768)
    const float* W      = (const float*)d_in[2];  // (1536,768)
    const float* bias   = (const float*)d_in[3];  // (768,)
    float* out = (float*)d_out;                   // (4,128,128,768)

    // 12 o-slices x 16 bricks = 192 blocks, 512 threads (8 waves, wave-specialized)
    fused_kernel<<<dim3(768 / TO, 16), 512, 0, stream>>>(input1, input2, W, bias, out);
}

// Round 6
// 268.318 us; speedup vs baseline: 1.1310x; 1.1032x over previous
//
#include <hip/hip_runtime.h>

typedef float f4    __attribute__((ext_vector_type(4)));
typedef float f32x4 __attribute__((ext_vector_type(4)));
typedef short short8 __attribute__((ext_vector_type(8)));
typedef unsigned short u16x4 __attribute__((ext_vector_type(4)));

#define NCHUNK 24   // 768 k / 32 per chunk

// f32 -> bf16 RNE, and the exact residual (x - bf16(x)) for the bf16x3 split.
__device__ inline unsigned short f2bf(float x) {
    union { float f; unsigned u; } v; v.f = x;
    return (unsigned short)((v.u + 0x7FFFu + ((v.u >> 16) & 1u)) >> 16);
}
__device__ inline float bf2f(unsigned short h) {
    union { unsigned u; float f; } v; v.u = ((unsigned)h) << 16;
    return v.f;
}

// Fused, MFMA-based. Block = (b, 64 n-rows, 64 m-rows, 64 o-cols); 512 thr / 8 waves.
// R5 counters showed the fp32-VALU GEMM was LDS-pipe-bound (12288 ds_read_b128/CU ~= 61us
// + 27us bank-conflict cycles; occupancy doubling was null). bf16x3 MFMA raises FMA per
// ds_read 16x and LDS is laid out in FRAGMENT order so every wave read is base+lane*16
// (linear, conflict-free). Accuracy: x=hi+lo bf16 split, P = hh+hl+lh, rel err ~2^-16.
//
// LDS fragment layout (per 32-k chunk): X[rt 0..7][kq 0..3][r 0..15][ki 0..7] bf16,
//   A: rt = row/16 (rows 0-63 = A1/n-tile, 64-127 = A2/m-tile), element (row, k=kq*8+ki)
//   B: rt = o/16  (o 0-63 = W1 cols,  64-127 = W2 cols),       element (o,  k=kq*8+ki)
// MFMA lane mapping (16x16x32): A: lane=A[l%16][(l/16)*8+e]; B: lane=B[(l/16)*8+e][l%16];
// D: row=(l>>4)*4+reg, col=l&15 [m89-verified]. Frag read addr = rt*1024B + lane*16B.
__global__ __launch_bounds__(512) void fused_kernel(
    const float* __restrict__ A1, const float* __restrict__ A2,
    const float* __restrict__ W, const float* __restrict__ bias,
    float* __restrict__ out)
{
    __shared__ union {
        struct {
            unsigned short Ah[4096], Al[4096], Bh[4096], Bl[4096];  // 4 x 8 KB
        } s;
        float p[128][68];   // rows 0-63: p1[n][o], 64-127: p2[m][o]; 34816 B
    } u;

    const int o0 = blockIdx.x * 64;      // 12 o-slices
    const int nm = blockIdx.y;           // 16 (b, n-tile, m-tile) bricks
    const int b  = nm >> 2;
    const int n0 = ((nm >> 1) & 1) * 64;
    const int m0 = (nm & 1) * 64;
    const int t    = threadIdx.x;        // 0..511
    const int lane = t & 63;
    const int w    = t >> 6;             // wave 0..7

    // ---- staging setup (per-thread constant) ----
    // A units (f4 along k): ids t, t+512. unit a: row_comb = a>>3, k0 = (a&7)*4.
    const float* aptr[2]; int a_dst[2];
    #pragma unroll
    for (int q = 0; q < 2; ++q) {
        const int a  = t + q * 512;
        const int rc = a >> 3;           // 0-63: A1 rows, 64-127: A2 rows
        const int k0 = (a & 7) * 4;
        const float* base = (rc < 64)
            ? (A1 + (size_t)(b * 128 + n0 + rc) * 768)
            : (A2 + (size_t)(b * 128 + m0 + (rc - 64)) * 768);
        aptr[q]  = base + k0;
        a_dst[q] = (rc >> 4) * 512 + (k0 >> 3) * 128 + (rc & 15) * 8 + (k0 & 7);
    }
    // B units (4 k at one o, strided loads are lane-coalesced): ids t, t+512.
    const float* bptr[2]; int b_dst[2];
    #pragma unroll
    for (int q = 0; q < 2; ++q) {
        const int v  = t + q * 512;
        const int oc = v & 127;          // 0-63: W1 col, 64-127: W2 col
        const int kk = (v >> 7) * 4;
        const int z  = oc >> 6;
        bptr[q]  = W + (size_t)(z * 768 + kk) * 768 + (o0 + (oc & 63));
        b_dst[q] = (oc >> 4) * 512 + (kk >> 3) * 128 + (oc & 15) * 8 + (kk & 7);
    }

    f4 rA[2]; float rB[2][4];
    #pragma unroll
    for (int q = 0; q < 2; ++q) {        // prologue: load chunk 0
        rA[q] = *(const f4*)(aptr[q]);
        #pragma unroll
        for (int j = 0; j < 4; ++j) rB[q][j] = bptr[q][(size_t)j * 768];
    }

    f32x4 acc[4] = {0, 0, 0, 0};

    for (int c = 0; c < NCHUNK; ++c) {
        // 1) convert + stage current regs -> LDS (first use: vmcnt wait lands here)
        #pragma unroll
        for (int q = 0; q < 2; ++q) {
            u16x4 h, l;
            #pragma unroll
            for (int j = 0; j < 4; ++j) {
                h[j] = f2bf(rA[q][j]);
                l[j] = f2bf(rA[q][j] - bf2f(h[j]));
            }
            *(u16x4*)&u.s.Ah[a_dst[q]] = h;
            *(u16x4*)&u.s.Al[a_dst[q]] = l;
        }
        #pragma unroll
        for (int q = 0; q < 2; ++q) {
            u16x4 h, l;
            #pragma unroll
            for (int j = 0; j < 4; ++j) {
                h[j] = f2bf(rB[q][j]);
                l[j] = f2bf(rB[q][j] - bf2f(h[j]));
            }
            *(u16x4*)&u.s.Bh[b_dst[q]] = h;
            *(u16x4*)&u.s.Bl[b_dst[q]] = l;
        }
        __syncthreads();                 // staging visible

        // 2) issue next chunk's loads; the MFMA phase below covers their latency
        if (c + 1 < NCHUNK) {
            const int k0 = (c + 1) * 32;
            #pragma unroll
            for (int q = 0; q < 2; ++q) {
                rA[q] = *(const f4*)(aptr[q] + k0);
                #pragma unroll
                for (int j = 0; j < 4; ++j)
                    rB[q][j] = bptr[q][(size_t)(k0 + j) * 768];
            }
        }

        // 3) MFMA: wave w owns output rows [w*16, w*16+16) of the stacked 128-row C
        {
            const short8 ah = *(const short8*)&u.s.Ah[w * 512 + lane * 8];
            const short8 al = *(const short8*)&u.s.Al[w * 512 + lane * 8];
            const int bt0 = (w >> 2) * 4;    // p1 waves read W1 frags, p2 waves W2
            #pragma unroll
            for (int ct = 0; ct < 4; ++ct) {
                const short8 bh = *(const short8*)&u.s.Bh[(bt0 + ct) * 512 + lane * 8];
                const short8 bl = *(const short8*)&u.s.Bl[(bt0 + ct) * 512 + lane * 8];
                acc[ct] = __builtin_amdgcn_mfma_f32_16x16x32_bf16(ah, bh, acc[ct], 0, 0, 0);
                acc[ct] = __builtin_amdgcn_mfma_f32_16x16x32_bf16(ah, bl, acc[ct], 0, 0, 0);
                acc[ct] = __builtin_amdgcn_mfma_f32_16x16x32_bf16(al, bh, acc[ct], 0, 0, 0);
            }
        }
        __syncthreads();                 // frag reads done; buffer reusable next iter
    }

    // park C in LDS: D row=(lane>>4)*4+i, col=lane&15 per tile
    #pragma unroll
    for (int ct = 0; ct < 4; ++ct)
        #pragma unroll
        for (int i = 0; i < 4; ++i)
            u.p[w * 16 + (lane >> 4) * 4 + i][ct * 16 + (lane & 15)] = acc[ct][i];
    __syncthreads();

    // egress (R5-proven): thread -> (2 n-rows, all 64 m, one f4 of o)
    const int o4 = (t & 15) * 4;
    const int nn = t >> 4;               // 0..31
    const f4 bb  = *(const f4*)(bias + o0 + o4);
    const f4 p1a = *(const f4*)&u.p[nn * 2 + 0][o4] + bb;
    const f4 p1b = *(const f4*)&u.p[nn * 2 + 1][o4] + bb;

    float* ob = out + ((size_t)(b * 128 + n0 + nn * 2) * 128 + m0) * 768 + o0 + o4;
    const size_t nstride = (size_t)128 * 768;

    #pragma unroll 4
    for (int m = 0; m < 64; ++m) {
        const f4 p2v = *(const f4*)&u.p[64 + m][o4];
        __builtin_nontemporal_store(p1a + p2v, (f4*)(ob + (size_t)m * 768));
        __builtin_nontemporal_store(p1b + p2v, (f4*)(ob + nstride + (size_t)m * 768));
    }
}

extern "C" void kernel_launch(void* const* d_in, const int* in_sizes, int n_in,
                              void* d_out, int out_size, void* d_ws, size_t ws_size,
                              hipStream_t stream)
{
    const float* input1 = (const float*)d_in[0];  // (4,128,768)
    const float* input2 = (const float*)d_in[1];  // (4,128,768)
    const float* W      = (const float*)d_in[2];  // (1536,768)
    const float* bias   = (const float*)d_in[3];  // (768,)
    float* out = (float*)d_out;                   // (4,128,128,768)

    fused_kernel<<<dim3(12, 16), 512, 0, stream>>>(input1, input2, W, bias, out);
}

// Round 7
// 243.260 us; speedup vs baseline: 1.2475x; 1.1030x over previous
//
#include <hip/hip_runtime.h>

typedef float f4    __attribute__((ext_vector_type(4)));
typedef float f32x4 __attribute__((ext_vector_type(4)));
typedef short short8 __attribute__((ext_vector_type(8)));
typedef unsigned short u16;
typedef unsigned short u16x4 __attribute__((ext_vector_type(4)));

#define NCHUNK 24   // 768 k / 32 per chunk

// ---- ws fragment layouts (u16 units) ----
// A_ws[g:16][c:24][hl:2][rt:4][kq:4][r:16][ki:8]
//   g = global_row>>6 (rows 0-511 = A1, 512-1023 = A2), rt=(row>>4)&3, r=row&15
//   c = k>>5, kq=(k>>3)&3, ki=k&7.  Strides: ki 1, r 8, kq 128, rt 512, hl 2048, c 4096, g 98304
// W_ws[c:24][panel:2][hl:2][rt:48][kq:4][r:16][ki:8]
//   panel = W row>=768, rt=o>>4, r=o&15. Strides: rt 512, hl 24576, panel 49152, c 98304
#define AWS_U16 1572864u   // 16*98304  (3.0 MB)
#define WWS_U16 2359296u   // 24*98304  (4.5 MB)

__device__ inline u16 f2bf(float x) {
    union { float f; unsigned u; } v; v.f = x;
    return (u16)((v.u + 0x7FFFu + ((v.u >> 16) & 1u)) >> 16);
}
__device__ inline float bf2f(u16 h) {
    union { unsigned u; float f; } v; v.u = ((unsigned)h) << 16;
    return v.f;
}

// Streaming pre-convert: f32 -> bf16 hi/lo pairs in FRAGMENT order.
// Hoists all conversion VALU + the k-transpose + the conflicted scatter out of the
// 24x-barriered GEMM loop (R6 evidence: GEMM phase ~60us vs ~25us model; the delta is
// in-loop cvt + 4/8-way ds_write conflicts + B's k-strided gather).
__global__ __launch_bounds__(512) void convert_kernel(
    const float* __restrict__ A1, const float* __restrict__ A2,
    const float* __restrict__ W, u16* __restrict__ Aws, u16* __restrict__ Wws)
{
    const int id = blockIdx.x * 512 + threadIdx.x;
    if (blockIdx.x < 384) {                 // A part: 196608 f4-units, reads coalesced
        const int u   = id;
        const int row = u / 192;
        const int k   = (u - row * 192) * 4;
        const float* src = (row < 512) ? (A1 + (size_t)row * 768 + k)
                                       : (A2 + (size_t)(row - 512) * 768 + k);
        const f4 v = *(const f4*)src;
        u16x4 h, l;
        #pragma unroll
        for (int j = 0; j < 4; ++j) { h[j] = f2bf(v[j]); l[j] = f2bf(v[j] - bf2f(h[j])); }
        const int g = row >> 6, rt = (row >> 4) & 3, r = row & 15;
        const int c = k >> 5, kq = (k >> 3) & 3, ki0 = k & 7;
        const size_t base = (size_t)g * 98304 + c * 4096 + rt * 512 + kq * 128 + r * 8 + ki0;
        *(u16x4*)&Aws[base]        = h;     // hl=0
        *(u16x4*)&Aws[base + 2048] = l;     // hl=1
    } else {                                // W part: 294912 units (4 k x 1 o each)
        const int u   = id - 384 * 512;
        const int o   = u % 768;            // consecutive lanes -> consecutive o: coalesced
        const int kk4 = u / 768;
        const int kk  = kk4 * 4;
        const int z   = (kk4 >= 192);       // panel
        const int k   = kk - z * 768;
        u16x4 h, l;
        #pragma unroll
        for (int j = 0; j < 4; ++j) {
            const float v = W[(size_t)(kk + j) * 768 + o];
            h[j] = f2bf(v); l[j] = f2bf(v - bf2f(h[j]));
        }
        const int rt = o >> 4, r = o & 15;
        const int c = k >> 5, kq = (k >> 3) & 3, ki0 = k & 7;
        const size_t base = (size_t)c * 98304 + (size_t)z * 49152
                          + rt * 512 + kq * 128 + r * 8 + ki0;
        *(u16x4*)&Wws[base]         = h;    // hl=0
        *(u16x4*)&Wws[base + 24576] = l;    // hl=1
    }
}

// MFMA GEMM + broadcast egress, staging from pre-converted fragment-order ws.
// Per chunk per thread: 4 contiguous f4 loads + 4 conflict-free ds_write_b128; one
// barrier per chunk (dbuf; loads issued BEFORE the MFMA phase, LDS writes after ->
// vmcnt wait covered by ~1300 cyc of DS/MFMA work). MFMA core/park/egress = R6 verbatim.
__global__ __launch_bounds__(512) void mfma_ws_kernel(
    const u16* __restrict__ Aws, const u16* __restrict__ Wws,
    const float* __restrict__ bias, float* __restrict__ out)
{
    // LDS slot (16384 u16 = 32 KB): [A1:4096][A2:4096][W1h:2048][W1l:2048][W2h:2048][W2l:2048]
    __shared__ union {
        u16   st[2][16384];                 // 64 KB double buffer
        float p[128][68];                   // C park, 34.8 KB (post-loop union reuse)
    } u;

    const int o0 = blockIdx.x * 64;         // 12 o-slices
    const int nm = blockIdx.y;              // 16 (b, n-half, m-half) bricks
    const int b  = nm >> 2, hn = (nm >> 1) & 1, hm = nm & 1;
    const int n0 = hn * 64, m0 = hm * 64;
    const int g_n = b * 2 + hn;             // A1 group
    const int g_m = 8 + b * 2 + hm;         // A2 group
    const int t = threadIdx.x, lane = t & 63, w = t >> 6;
    const int rt0 = blockIdx.x * 4;         // W rt window
    const int r2  = t >> 8;                 // 0 -> hi stream, 1 -> lo stream
    const int t8  = (t & 255) * 8;

    const u16* sA1 = Aws + (size_t)g_n * 98304 + t * 8;
    const u16* sA2 = Aws + (size_t)g_m * 98304 + t * 8;
    const u16* sW1 = Wws + (size_t)r2 * 24576 + rt0 * 512 + t8;
    const u16* sW2 = sW1 + 49152;

    // prologue: chunk 0 -> slot 0
    f4 rA1 = *(const f4*)(sA1);
    f4 rA2 = *(const f4*)(sA2);
    f4 rW1 = *(const f4*)(sW1);
    f4 rW2 = *(const f4*)(sW2);
    *(f4*)&u.st[0][t * 8]                  = rA1;
    *(f4*)&u.st[0][4096 + t * 8]           = rA2;
    *(f4*)&u.st[0][8192 + r2 * 2048 + t8]  = rW1;
    *(f4*)&u.st[0][12288 + r2 * 2048 + t8] = rW2;
    __syncthreads();

    f32x4 acc[4] = {0, 0, 0, 0};

    for (int c = 0; c < NCHUNK; ++c) {
        const int s = c & 1;
        if (c + 1 < NCHUNK) {               // 1) issue next chunk's loads (contiguous 16B)
            rA1 = *(const f4*)(sA1 + (size_t)(c + 1) * 4096);
            rA2 = *(const f4*)(sA2 + (size_t)(c + 1) * 4096);
            rW1 = *(const f4*)(sW1 + (size_t)(c + 1) * 98304);
            rW2 = *(const f4*)(sW2 + (size_t)(c + 1) * 98304);
        }
        // 2) MFMA on slot s (reads are lane-contiguous b128: conflict-free)
        {
            const u16* S  = u.st[s];
            const u16* ab = (w < 4) ? (S + w * 512) : (S + 4096 + (w - 4) * 512);
            const short8 ah = *(const short8*)(ab + lane * 8);
            const short8 al = *(const short8*)(ab + 2048 + lane * 8);
            const u16* Bb = (w < 4) ? (S + 8192) : (S + 12288);
            #pragma unroll
            for (int ct = 0; ct < 4; ++ct) {
                const short8 bh = *(const short8*)(Bb + ct * 512 + lane * 8);
                const short8 bl = *(const short8*)(Bb + 2048 + ct * 512 + lane * 8);
                acc[ct] = __builtin_amdgcn_mfma_f32_16x16x32_bf16(ah, bh, acc[ct], 0, 0, 0);
                acc[ct] = __builtin_amdgcn_mfma_f32_16x16x32_bf16(ah, bl, acc[ct], 0, 0, 0);
                acc[ct] = __builtin_amdgcn_mfma_f32_16x16x32_bf16(al, bh, acc[ct], 0, 0, 0);
            }
        }
        // 3) stage regs -> other slot (vmcnt wait lands here, after the MFMA phase)
        if (c + 1 < NCHUNK) {
            const int ns = s ^ 1;
            *(f4*)&u.st[ns][t * 8]                  = rA1;
            *(f4*)&u.st[ns][4096 + t * 8]           = rA2;
            *(f4*)&u.st[ns][8192 + r2 * 2048 + t8]  = rW1;
            *(f4*)&u.st[ns][12288 + r2 * 2048 + t8] = rW2;
            __syncthreads();                // single barrier per chunk
        }
    }
    __syncthreads();                        // all frag reads done before union reuse

    // park C (R6-verified D mapping: row=(lane>>4)*4+i, col=lane&15)
    #pragma unroll
    for (int ct = 0; ct < 4; ++ct)
        #pragma unroll
        for (int i = 0; i < 4; ++i)
            u.p[w * 16 + (lane >> 4) * 4 + i][ct * 16 + (lane & 15)] = acc[ct][i];
    __syncthreads();

    // egress (R6-verbatim): thread -> (2 n-rows, all 64 m, one f4 of o)
    const int o4 = (t & 15) * 4;
    const int nn = t >> 4;                  // 0..31
    const f4 bb  = *(const f4*)(bias + o0 + o4);
    const f4 p1a = *(const f4*)&u.p[nn * 2 + 0][o4] + bb;
    const f4 p1b = *(const f4*)&u.p[nn * 2 + 1][o4] + bb;

    float* ob = out + ((size_t)(b * 128 + n0 + nn * 2) * 128 + m0) * 768 + o0 + o4;
    const size_t nstride = (size_t)128 * 768;

    #pragma unroll 4
    for (int m = 0; m < 64; ++m) {
        const f4 p2v = *(const f4*)&u.p[64 + m][o4];
        __builtin_nontemporal_store(p1a + p2v, (f4*)(ob + (size_t)m * 768));
        __builtin_nontemporal_store(p1b + p2v, (f4*)(ob + nstride + (size_t)m * 768));
    }
}

// ---------------- fallback: R6 kernel verbatim (passed @ absmax 0.015625) ----------------
__global__ __launch_bounds__(512) void fused_v6(
    const float* __restrict__ A1, const float* __restrict__ A2,
    const float* __restrict__ W, const float* __restrict__ bias,
    float* __restrict__ out)
{
    __shared__ union {
        struct { u16 Ah[4096], Al[4096], Bh[4096], Bl[4096]; } s;
        float p[128][68];
    } u;

    const int o0 = blockIdx.x * 64;
    const int nm = blockIdx.y;
    const int b  = nm >> 2;
    const int n0 = ((nm >> 1) & 1) * 64;
    const int m0 = (nm & 1) * 64;
    const int t = threadIdx.x, lane = t & 63, w = t >> 6;

    const float* aptr[2]; int a_dst[2];
    #pragma unroll
    for (int q = 0; q < 2; ++q) {
        const int a = t + q * 512, rc = a >> 3, k0 = (a & 7) * 4;
        const float* base = (rc < 64) ? (A1 + (size_t)(b * 128 + n0 + rc) * 768)
                                      : (A2 + (size_t)(b * 128 + m0 + (rc - 64)) * 768);
        aptr[q] = base + k0;
        a_dst[q] = (rc >> 4) * 512 + (k0 >> 3) * 128 + (rc & 15) * 8 + (k0 & 7);
    }
    const float* bptr[2]; int b_dst[2];
    #pragma unroll
    for (int q = 0; q < 2; ++q) {
        const int v = t + q * 512, oc = v & 127, kk = (v >> 7) * 4, z = oc >> 6;
        bptr[q] = W + (size_t)(z * 768 + kk) * 768 + (o0 + (oc & 63));
        b_dst[q] = (oc >> 4) * 512 + (kk >> 3) * 128 + (oc & 15) * 8 + (kk & 7);
    }

    f4 rA[2]; float rB[2][4];
    #pragma unroll
    for (int q = 0; q < 2; ++q) {
        rA[q] = *(const f4*)(aptr[q]);
        #pragma unroll
        for (int j = 0; j < 4; ++j) rB[q][j] = bptr[q][(size_t)j * 768];
    }

    f32x4 acc[4] = {0, 0, 0, 0};
    for (int c = 0; c < NCHUNK; ++c) {
        #pragma unroll
        for (int q = 0; q < 2; ++q) {
            u16x4 h, l;
            #pragma unroll
            for (int j = 0; j < 4; ++j) { h[j] = f2bf(rA[q][j]); l[j] = f2bf(rA[q][j] - bf2f(h[j])); }
            *(u16x4*)&u.s.Ah[a_dst[q]] = h; *(u16x4*)&u.s.Al[a_dst[q]] = l;
        }
        #pragma unroll
        for (int q = 0; q < 2; ++q) {
            u16x4 h, l;
            #pragma unroll
            for (int j = 0; j < 4; ++j) { h[j] = f2bf(rB[q][j]); l[j] = f2bf(rB[q][j] - bf2f(h[j])); }
            *(u16x4*)&u.s.Bh[b_dst[q]] = h; *(u16x4*)&u.s.Bl[b_dst[q]] = l;
        }
        __syncthreads();
        if (c + 1 < NCHUNK) {
            const int k0 = (c + 1) * 32;
            #pragma unroll
            for (int q = 0; q < 2; ++q) {
                rA[q] = *(const f4*)(aptr[q] + k0);
                #pragma unroll
                for (int j = 0; j < 4; ++j) rB[q][j] = bptr[q][(size_t)(k0 + j) * 768];
            }
        }
        {
            const short8 ah = *(const short8*)&u.s.Ah[w * 512 + lane * 8];
            const short8 al = *(const short8*)&u.s.Al[w * 512 + lane * 8];
            const int bt0 = (w >> 2) * 4;
            #pragma unroll
            for (int ct = 0; ct < 4; ++ct) {
                const short8 bh = *(const short8*)&u.s.Bh[(bt0 + ct) * 512 + lane * 8];
                const short8 bl = *(const short8*)&u.s.Bl[(bt0 + ct) * 512 + lane * 8];
                acc[ct] = __builtin_amdgcn_mfma_f32_16x16x32_bf16(ah, bh, acc[ct], 0, 0, 0);
                acc[ct] = __builtin_amdgcn_mfma_f32_16x16x32_bf16(ah, bl, acc[ct], 0, 0, 0);
                acc[ct] = __builtin_amdgcn_mfma_f32_16x16x32_bf16(al, bh, acc[ct], 0, 0, 0);
            }
        }
        __syncthreads();
    }
    #pragma unroll
    for (int ct = 0; ct < 4; ++ct)
        #pragma unroll
        for (int i = 0; i < 4; ++i)
            u.p[w * 16 + (lane >> 4) * 4 + i][ct * 16 + (lane & 15)] = acc[ct][i];
    __syncthreads();

    const int o4 = (t & 15) * 4, nn = t >> 4;
    const f4 bb  = *(const f4*)(bias + o0 + o4);
    const f4 p1a = *(const f4*)&u.p[nn * 2 + 0][o4] + bb;
    const f4 p1b = *(const f4*)&u.p[nn * 2 + 1][o4] + bb;
    float* ob = out + ((size_t)(b * 128 + n0 + nn * 2) * 128 + m0) * 768 + o0 + o4;
    const size_t nstride = (size_t)128 * 768;
    #pragma unroll 4
    for (int m = 0; m < 64; ++m) {
        const f4 p2v = *(const f4*)&u.p[64 + m][o4];
        __builtin_nontemporal_store(p1a + p2v, (f4*)(ob + (size_t)m * 768));
        __builtin_nontemporal_store(p1b + p2v, (f4*)(ob + nstride + (size_t)m * 768));
    }
}

extern "C" void kernel_launch(void* const* d_in, const int* in_sizes, int n_in,
                              void* d_out, int out_size, void* d_ws, size_t ws_size,
                              hipStream_t stream)
{
    const float* input1 = (const float*)d_in[0];  // (4,128,768)
    const float* input2 = (const float*)d_in[1];  // (4,128,768)
    const float* W      = (const float*)d_in[2];  // (1536,768)
    const float* bias   = (const float*)d_in[3];  // (768,)
    float* out = (float*)d_out;                   // (4,128,128,768)

    const size_t need = (size_t)(AWS_U16 + WWS_U16) * sizeof(u16);  // 7.86 MB

    if (ws_size >= need) {
        u16* Aws = (u16*)d_ws;
        u16* Wws = Aws + AWS_U16;
        convert_kernel<<<dim3(960), 512, 0, stream>>>(input1, input2, W, Aws, Wws);
        mfma_ws_kernel<<<dim3(12, 16), 512, 0, stream>>>(Aws, Wws, bias, out);
    } else {
        fused_v6<<<dim3(12, 16), 512, 0, stream>>>(input1, input2, W, bias, out);
    }
}